// Round 19
// baseline (501.658 us; speedup 1.0000x reference)
//
#include <hip/hip_runtime.h>

#define SEQL 4096
#define NB 64

// ---------------------------------------------------------------------------
// DPP quad-reductions (VALU pipe, no DS ops).
// ---------------------------------------------------------------------------
__device__ __forceinline__ float dpp_xor1_add(float x) {
    int v = __builtin_amdgcn_mov_dpp(__float_as_int(x), 0xB1, 0xF, 0xF, true);
    return x + __int_as_float(v);
}
__device__ __forceinline__ float dpp_xor2_add(float x) {
    int v = __builtin_amdgcn_mov_dpp(__float_as_int(x), 0x4E, 0xF, 0xF, true);
    return x + __int_as_float(v);
}

// ---------------------------------------------------------------------------
// Shared helpers: 4x4-tile GEMM on 64x68 LDS buffers.
// ---------------------------------------------------------------------------
#define FMA16(A, W, H)                                      \
    A[0]  = fmaf(W.x, H.x, A[0]);  A[1]  = fmaf(W.x, H.y, A[1]);   \
    A[2]  = fmaf(W.x, H.z, A[2]);  A[3]  = fmaf(W.x, H.w, A[3]);   \
    A[4]  = fmaf(W.y, H.x, A[4]);  A[5]  = fmaf(W.y, H.y, A[5]);   \
    A[6]  = fmaf(W.y, H.z, A[6]);  A[7]  = fmaf(W.y, H.w, A[7]);   \
    A[8]  = fmaf(W.z, H.x, A[8]);  A[9]  = fmaf(W.z, H.y, A[9]);   \
    A[10] = fmaf(W.z, H.z, A[10]); A[11] = fmaf(W.z, H.w, A[11]);  \
    A[12] = fmaf(W.w, H.x, A[12]); A[13] = fmaf(W.w, H.y, A[13]);  \
    A[14] = fmaf(W.w, H.z, A[14]); A[15] = fmaf(W.w, H.w, A[15])

__device__ __forceinline__ void proj_tile64(const float* __restrict__ sW,
                                            const float* __restrict__ sA,
                                            int jq, int tq, float* __restrict__ a)
{
#pragma unroll
    for (int u = 0; u < 16; ++u) a[u] = 0.f;
#pragma unroll 4
    for (int i = 0; i < 64; ++i) {
        float4 w  = *reinterpret_cast<const float4*>(&sW[i * 68 + jq]);
        float4 h4 = *reinterpret_cast<const float4*>(&sA[i * 68 + tq]);
        FMA16(a, w, h4);
    }
}

// transposed weight stage, split into load (regs) and write (LDS) halves.
__device__ __forceinline__ void load_w_t(const float* __restrict__ W, int ldw, int col0,
                                         int tid, float4* __restrict__ r)
{
    const int j = tid & 63;
    const int cq0 = tid >> 6;
#pragma unroll
    for (int it = 0; it < 4; ++it)
        r[it] = *reinterpret_cast<const float4*>(&W[(size_t)j * ldw + col0 + (it * 4 + cq0) * 4]);
}
__device__ __forceinline__ void write_w_t(const float4* __restrict__ r,
                                          float* __restrict__ sWb, int tid)
{
    const int j = tid & 63;
    const int cq0 = tid >> 6;
#pragma unroll
    for (int it = 0; it < 4; ++it) {
        const int c = (it * 4 + cq0) * 4;
        sWb[(c + 0) * 68 + j] = r[it].x;
        sWb[(c + 1) * 68 + j] = r[it].y;
        sWb[(c + 2) * 68 + j] = r[it].z;
        sWb[(c + 3) * 68 + j] = r[it].w;
    }
}

__device__ __forceinline__ void stage_w_t(const float* __restrict__ W, int ldw, int col0,
                                          float* __restrict__ sWb, int tid)
{
    float4 r[4];
    load_w_t(W, ldw, col0, tid, r);
    write_w_t(r, sWb, tid);
}
__device__ __forceinline__ void stage_w_n(const float* __restrict__ W,
                                          float* __restrict__ sWb, int tid)
{
#pragma unroll
    for (int it = 0; it < 4; ++it) {
        int item = it * 256 + tid;
        int r = item >> 4, c4 = item & 15;
        float4 w = *reinterpret_cast<const float4*>(&W[(size_t)r * 64 + c4 * 4]);
        *reinterpret_cast<float4*>(&sWb[r * 68 + c4 * 4]) = w;
    }
}

// ---------------------------------------------------------------------------
// Encoder v6 (unchanged).
// ---------------------------------------------------------------------------
__global__ __launch_bounds__(256) void encoder_kernel(
    const int* __restrict__ x, const float* __restrict__ embed,
    const float* __restrict__ W1, const float* __restrict__ b1,
    const float* __restrict__ W2, const float* __restrict__ b2,
    const float* __restrict__ ln_g, const float* __restrict__ ln_b,
    const float* __restrict__ Wk, const float* __restrict__ Wv,
    const float* __restrict__ Wq,
    float* __restrict__ ks, float* __restrict__ vs,
    float* __restrict__ hidT, float* __restrict__ qlast)
{
    __shared__ __align__(16) float sZ[64 * 68];
    __shared__ __align__(16) float sF[64 * 68];
    __shared__ __align__(16) float sW[64 * 68];

    const int tid = threadIdx.x;
    const size_t g0 = (size_t)blockIdx.x * 64;
    const int b = (int)(g0 >> 12);
    const int l0 = (int)(g0 & (SEQL - 1));
    const int jq = (tid & 15) * 4;
    const int tq = (tid >> 4) * 4;
    const bool doq = (l0 < 2048);
    const bool dolast = (l0 == SEQL - 64);

    float4 pf[4], pf2[4];

    load_w_t(W1, 64, 0, tid, pf);
    for (int idx = tid; idx < 4096; idx += 256) {
        int t = idx >> 6, i = idx & 63;
        sZ[i * 68 + t] = embed[(size_t)x[g0 + t] * 64 + i];
    }
    write_w_t(pf, sW, tid);
    load_w_t(W2, 128, 0, tid, pf2);
    __syncthreads();                                   // (1)

    float zacc[16];
#pragma unroll
    for (int u = 0; u < 16; ++u) zacc[u] = 0.f;

    {
        float a[16];
        proj_tile64(sW, sZ, jq, tq, a);
        float4 bb = *reinterpret_cast<const float4*>(&b1[jq]);
        float bv[4] = {bb.x, bb.y, bb.z, bb.w};
#pragma unroll
        for (int u = 0; u < 4; ++u) {
            float4 o;
            o.x = fmaxf(a[u * 4 + 0] + bv[u], 0.f);
            o.y = fmaxf(a[u * 4 + 1] + bv[u], 0.f);
            o.z = fmaxf(a[u * 4 + 2] + bv[u], 0.f);
            o.w = fmaxf(a[u * 4 + 3] + bv[u], 0.f);
            *reinterpret_cast<float4*>(&sF[(jq + u) * 68 + tq]) = o;
        }
    }
    __syncthreads();                                   // (2)
    write_w_t(pf2, sW, tid);
    load_w_t(W1 + 4096, 64, 0, tid, pf);
    __syncthreads();                                   // (3)
#pragma unroll 4
    for (int p = 0; p < 64; ++p) {
        float4 w  = *reinterpret_cast<const float4*>(&sW[p * 68 + jq]);
        float4 f4 = *reinterpret_cast<const float4*>(&sF[p * 68 + tq]);
        FMA16(zacc, w, f4);
    }
    __syncthreads();                                   // (4)
    write_w_t(pf, sW, tid);
    load_w_t(W2, 128, 64, tid, pf2);
    __syncthreads();                                   // (5)
    {
        float a[16];
        proj_tile64(sW, sZ, jq, tq, a);
        float4 bb = *reinterpret_cast<const float4*>(&b1[64 + jq]);
        float bv[4] = {bb.x, bb.y, bb.z, bb.w};
#pragma unroll
        for (int u = 0; u < 4; ++u) {
            float4 o;
            o.x = fmaxf(a[u * 4 + 0] + bv[u], 0.f);
            o.y = fmaxf(a[u * 4 + 1] + bv[u], 0.f);
            o.z = fmaxf(a[u * 4 + 2] + bv[u], 0.f);
            o.w = fmaxf(a[u * 4 + 3] + bv[u], 0.f);
            *reinterpret_cast<float4*>(&sF[(jq + u) * 68 + tq]) = o;
        }
    }
    __syncthreads();                                   // (6)
    write_w_t(pf2, sW, tid);
    load_w_t(Wk, 64, 0, tid, pf);
    load_w_t(Wv, 64, 0, tid, pf2);
    __syncthreads();                                   // (7)
#pragma unroll 4
    for (int p = 0; p < 64; ++p) {
        float4 w  = *reinterpret_cast<const float4*>(&sW[p * 68 + jq]);
        float4 f4 = *reinterpret_cast<const float4*>(&sF[p * 68 + tq]);
        FMA16(zacc, w, f4);
    }

    {
        float z[16];
        float4 b2v = *reinterpret_cast<const float4*>(&b2[jq]);
        float bv[4] = {b2v.x, b2v.y, b2v.z, b2v.w};
#pragma unroll
        for (int u = 0; u < 4; ++u) {
            float4 h4 = *reinterpret_cast<const float4*>(&sZ[(jq + u) * 68 + tq]);
            z[u * 4 + 0] = h4.x + bv[u] + zacc[u * 4 + 0];
            z[u * 4 + 1] = h4.y + bv[u] + zacc[u * 4 + 1];
            z[u * 4 + 2] = h4.z + bv[u] + zacc[u * 4 + 2];
            z[u * 4 + 3] = h4.w + bv[u] + zacc[u * 4 + 3];
        }
        float s[4], ss[4];
#pragma unroll
        for (int v = 0; v < 4; ++v) {
            s[v]  = z[v] + z[4 + v] + z[8 + v] + z[12 + v];
            ss[v] = z[v] * z[v] + z[4 + v] * z[4 + v]
                  + z[8 + v] * z[8 + v] + z[12 + v] * z[12 + v];
        }
#pragma unroll
        for (int m = 1; m <= 8; m <<= 1) {
#pragma unroll
            for (int v = 0; v < 4; ++v) {
                s[v]  += __shfl_xor(s[v], m);
                ss[v] += __shfl_xor(ss[v], m);
            }
        }
        float mu[4], inv[4];
#pragma unroll
        for (int v = 0; v < 4; ++v) {
            mu[v] = s[v] * 0.015625f;
            float var = ss[v] * 0.015625f - mu[v] * mu[v];
            inv[v] = rsqrtf(var + 1e-5f);
        }
        float4 g4  = *reinterpret_cast<const float4*>(&ln_g[jq]);
        float4 be4 = *reinterpret_cast<const float4*>(&ln_b[jq]);
        float gv[4] = {g4.x, g4.y, g4.z, g4.w};
        float bev[4] = {be4.x, be4.y, be4.z, be4.w};
#pragma unroll
        for (int u = 0; u < 4; ++u) {
            float4 o;
            o.x = (z[u * 4 + 0] - mu[0]) * inv[0] * gv[u] + bev[u];
            o.y = (z[u * 4 + 1] - mu[1]) * inv[1] * gv[u] + bev[u];
            o.z = (z[u * 4 + 2] - mu[2]) * inv[2] * gv[u] + bev[u];
            o.w = (z[u * 4 + 3] - mu[3]) * inv[3] * gv[u] + bev[u];
            *reinterpret_cast<float4*>(&sZ[(jq + u) * 68 + tq]) = o;
        }
    }
    __syncthreads();                                   // (8)
    write_w_t(pf, sW, tid);                            // sW = Wk
    write_w_t(pf2, sF, tid);                           // sF = Wv
    if (dolast) load_w_t(Wq, 64, 0, tid, pf);
    __syncthreads();                                   // (9)

    // k projection + l2norm
    {
        float a[16];
        proj_tile64(sW, sZ, jq, tq, a);
        float ssq[4];
#pragma unroll
        for (int v = 0; v < 4; ++v)
            ssq[v] = a[v] * a[v] + a[4 + v] * a[4 + v]
                   + a[8 + v] * a[8 + v] + a[12 + v] * a[12 + v];
#pragma unroll
        for (int m = 1; m <= 8; m <<= 1) {
#pragma unroll
            for (int v = 0; v < 4; ++v) ssq[v] += __shfl_xor(ssq[v], m);
        }
#pragma unroll
        for (int v = 0; v < 4; ++v) {
            float sc = 1.f / fmaxf(sqrtf(ssq[v]), 1e-12f);
            float4 o = make_float4(a[v] * sc, a[4 + v] * sc, a[8 + v] * sc, a[12 + v] * sc);
            *reinterpret_cast<float4*>(&ks[(g0 + tq + v) * 64 + jq]) = o;
        }
    }
    // v projection
    {
        float a[16];
        proj_tile64(sF, sZ, jq, tq, a);
#pragma unroll
        for (int v = 0; v < 4; ++v) {
            float4 o = make_float4(a[v], a[4 + v], a[8 + v], a[12 + v]);
            *reinterpret_cast<float4*>(&vs[(g0 + tq + v) * 64 + jq]) = o;
        }
    }

    // hidden -> hidT (channel-major [b][i][l]; coalesced float4 rows)
    if (doq) {
#pragma unroll
        for (int it = 0; it < 4; ++it) {
            int item = it * 256 + tid;
            int i = item >> 4, q4 = (item & 15) * 4;
            float4 v = *reinterpret_cast<const float4*>(&sZ[i * 68 + q4]);
            *reinterpret_cast<float4*>(&hidT[((size_t)b * 64 + i) * 2048 + l0 + q4]) = v;
        }
    }

    if (dolast) {
        __syncthreads();                               // (10)
        write_w_t(pf, sW, tid);
        __syncthreads();                               // (11)
        float a[16];
        proj_tile64(sW, sZ, jq, tq, a);
        if ((tid >> 4) == 15) {
            float4 o = make_float4(a[3], a[7], a[11], a[15]);
            *reinterpret_cast<float4*>(&qlast[(size_t)b * 64 + jq]) = o;
        }
    }
}

// ---------------------------------------------------------------------------
// Chunked delta scan, phase A (round-11 version) + deterministic zeroing of
// the per-batch combine counters (jobs 0..63; chunk fully precedes combine
// in stream order).
// ---------------------------------------------------------------------------
#define STEP2(K0, K1, K2, K3, V)                                                \
    do {                                                                        \
        float dp0 = fmaf(p[0], K0.x, fmaf(p[1], K0.y, fmaf(p[2], K0.z, p[3] * K0.w))); \
        float dp1 = fmaf(p[4], K1.x, fmaf(p[5], K1.y, fmaf(p[6], K1.z, p[7] * K1.w))); \
        float dp2 = fmaf(p[8], K2.x, fmaf(p[9], K2.y, fmaf(p[10], K2.z, p[11] * K2.w))); \
        float dp3 = fmaf(p[12], K3.x, fmaf(p[13], K3.y, fmaf(p[14], K3.z, p[15] * K3.w))); \
        float dq0 = fmaf(q[0], K0.x, fmaf(q[1], K0.y, fmaf(q[2], K0.z, q[3] * K0.w))); \
        float dq1 = fmaf(q[4], K1.x, fmaf(q[5], K1.y, fmaf(q[6], K1.z, q[7] * K1.w))); \
        float dq2 = fmaf(q[8], K2.x, fmaf(q[9], K2.y, fmaf(q[10], K2.z, q[11] * K2.w))); \
        float dq3 = fmaf(q[12], K3.x, fmaf(q[13], K3.y, fmaf(q[14], K3.z, q[15] * K3.w))); \
        float ddp = (dp0 + dp1) + (dp2 + dp3);                                  \
        float ddq = (dq0 + dq1) + (dq2 + dq3);                                  \
        ddp = dpp_xor1_add(ddp);  ddq = dpp_xor1_add(ddq);                      \
        ddp = dpp_xor2_add(ddp);  ddq = dpp_xor2_add(ddq);                      \
        float up = -ddp;                                                        \
        float uq = V - ddq;                                                     \
        p[0] = fmaf(up, K0.x, p[0]);   q[0] = fmaf(uq, K0.x, q[0]);             \
        p[1] = fmaf(up, K0.y, p[1]);   q[1] = fmaf(uq, K0.y, q[1]);             \
        p[2] = fmaf(up, K0.z, p[2]);   q[2] = fmaf(uq, K0.z, q[2]);             \
        p[3] = fmaf(up, K0.w, p[3]);   q[3] = fmaf(uq, K0.w, q[3]);             \
        p[4] = fmaf(up, K1.x, p[4]);   q[4] = fmaf(uq, K1.x, q[4]);             \
        p[5] = fmaf(up, K1.y, p[5]);   q[5] = fmaf(uq, K1.y, q[5]);             \
        p[6] = fmaf(up, K1.z, p[6]);   q[6] = fmaf(uq, K1.z, q[6]);             \
        p[7] = fmaf(up, K1.w, p[7]);   q[7] = fmaf(uq, K1.w, q[7]);             \
        p[8] = fmaf(up, K2.x, p[8]);   q[8] = fmaf(uq, K2.x, q[8]);             \
        p[9] = fmaf(up, K2.y, p[9]);   q[9] = fmaf(uq, K2.y, q[9]);             \
        p[10] = fmaf(up, K2.z, p[10]); q[10] = fmaf(uq, K2.z, q[10]);           \
        p[11] = fmaf(up, K2.w, p[11]); q[11] = fmaf(uq, K2.w, q[11]);           \
        p[12] = fmaf(up, K3.x, p[12]); q[12] = fmaf(uq, K3.x, q[12]);           \
        p[13] = fmaf(up, K3.y, p[13]); q[13] = fmaf(uq, K3.y, q[13]);           \
        p[14] = fmaf(up, K3.z, p[14]); q[14] = fmaf(uq, K3.z, q[14]);           \
        p[15] = fmaf(up, K3.w, p[15]); q[15] = fmaf(uq, K3.w, q[15]);           \
    } while (0)

__global__ __launch_bounds__(256) void chunk_kernel(
    float* __restrict__ ksb, float* __restrict__ vsb, int C, int* __restrict__ cnt)
{
    __shared__ __align__(16) float sk[2][32 * 64];
    __shared__ __align__(16) float sv[2][32 * 64];

    const int job = blockIdx.x;
    const int tid = threadIdx.x;
    const int r = tid >> 2;
    const int c0 = (tid & 3) * 16;
    float* kc = ksb + (size_t)job * C * 64;
    float* vc = vsb + (size_t)job * C * 64;

    if (tid == 0 && job < NB) cnt[job] = 0;   // reset combine counters

    float p[16], q[16];
#pragma unroll
    for (int j = 0; j < 16; ++j) { p[j] = (c0 + j == r) ? 1.f : 0.f; q[j] = 0.f; }

    const int nt = C >> 5;
    float4 rk0, rk1, rv0, rv1;

    {
        const float4* gk = reinterpret_cast<const float4*>(kc);
        const float4* gv = reinterpret_cast<const float4*>(vc);
        float4 a0 = gk[tid], a1 = gk[256 + tid];
        float4 b0 = gv[tid], b1 = gv[256 + tid];
        float4* dk = reinterpret_cast<float4*>(sk[0]);
        float4* dv = reinterpret_cast<float4*>(sv[0]);
        dk[tid] = a0; dk[256 + tid] = a1;
        dv[tid] = b0; dv[256 + tid] = b1;
    }
    if (nt > 1) {
        const float4* gk = reinterpret_cast<const float4*>(kc + 2048);
        const float4* gv = reinterpret_cast<const float4*>(vc + 2048);
        rk0 = gk[tid]; rk1 = gk[256 + tid];
        rv0 = gv[tid]; rv1 = gv[256 + tid];
    }
    __syncthreads();

    int cur = 0;
    for (int tile = 0; tile < nt; ++tile) {
        if (tile + 1 < nt) {
            float4* dk = reinterpret_cast<float4*>(sk[cur ^ 1]);
            float4* dv = reinterpret_cast<float4*>(sv[cur ^ 1]);
            dk[tid] = rk0; dk[256 + tid] = rk1;
            dv[tid] = rv0; dv[256 + tid] = rv1;
            if (tile + 2 < nt) {
                const float4* gk = reinterpret_cast<const float4*>(kc + (size_t)(tile + 2) * 2048);
                const float4* gv = reinterpret_cast<const float4*>(vc + (size_t)(tile + 2) * 2048);
                rk0 = gk[tid]; rk1 = gk[256 + tid];
                rv0 = gv[tid]; rv1 = gv[256 + tid];
            }
        }

        const float* kl = sk[cur] + c0;
        const float* vl = sv[cur] + r;
        float4 a0, a1, a2, a3, e0, e1, e2, e3;
        float va, ve;
        {
            const float4* kp = reinterpret_cast<const float4*>(kl);
            a0 = kp[0]; a1 = kp[1]; a2 = kp[2]; a3 = kp[3];
            va = vl[0];
        }
#pragma unroll
        for (int t = 0; t < 32; t += 2) {
            {
                const float4* kp = reinterpret_cast<const float4*>(kl + (t + 1) * 64);
                e0 = kp[0]; e1 = kp[1]; e2 = kp[2]; e3 = kp[3];
                ve = vl[(t + 1) * 64];
            }
            STEP2(a0, a1, a2, a3, va);
            if (t + 2 < 32) {
                const float4* kp = reinterpret_cast<const float4*>(kl + (t + 2) * 64);
                a0 = kp[0]; a1 = kp[1]; a2 = kp[2]; a3 = kp[3];
                va = vl[(t + 2) * 64];
            }
            STEP2(e0, e1, e2, e3, ve);
        }
        __syncthreads();
        cur ^= 1;
    }

    float4* po = reinterpret_cast<float4*>(kc + r * 64 + c0);
    po[0] = make_float4(p[0], p[1], p[2], p[3]);
    po[1] = make_float4(p[4], p[5], p[6], p[7]);
    po[2] = make_float4(p[8], p[9], p[10], p[11]);
    po[3] = make_float4(p[12], p[13], p[14], p[15]);
    float4* qo = reinterpret_cast<float4*>(vc + r * 64 + c0);
    qo[0] = make_float4(q[0], q[1], q[2], q[3]);
    qo[1] = make_float4(q[4], q[5], q[6], q[7]);
    qo[2] = make_float4(q[8], q[9], q[10], q[11]);
    qo[3] = make_float4(q[12], q[13], q[14], q[15]);
}

// ---------------------------------------------------------------------------
// Combine (scan 1, row-split x4) + FUSED precompute: the last of each
// batch's 4 blocks (atomic counter) re-reads the completed M and computes
// WAM = Wattn^T M, MK = Wk M, MV = Wv M in re-carved LDS.
// ---------------------------------------------------------------------------
__global__ __launch_bounds__(256) void combine_kernel(
    const float* __restrict__ Pb, const float* __restrict__ Qb,
    float* __restrict__ Mout, int nc, int chunk_stride,
    const float* __restrict__ Wattn, const float* __restrict__ Wk,
    const float* __restrict__ Wv,
    float* __restrict__ WAM, float* __restrict__ MK, float* __restrict__ MV,
    int* __restrict__ cnt)
{
    // flat LDS, carved two ways:
    //  combine phase:   sP = lds[0..8191] (2x4096), sMl = lds[8192..10367] (2x1088)
    //  precompute phase: pcM = lds[0..4351], pcOp = lds[4352..8703]
    __shared__ __align__(16) float lds[10368];
    __shared__ int sWin;
    float* sP  = lds;
    float* sMl = lds + 8192;

    const int bb = blockIdx.x;
    const int b = bb >> 2;
    const int r0 = (bb & 3) << 4;
    const int tid = threadIdx.x;
    const int rl = tid >> 4;
    const int j4 = (tid & 15) * 4;
    const int gr = r0 + rl;

    *reinterpret_cast<float4*>(&sMl[rl * 68 + j4]) = make_float4(0.f, 0.f, 0.f, 0.f);
    {
        const float4* g = reinterpret_cast<const float4*>(Pb + (size_t)b * nc * chunk_stride);
        float4* s = reinterpret_cast<float4*>(sP);
        for (int i = tid; i < 1024; i += 256) s[i] = g[i];
    }
    __syncthreads();

    int cur = 0;
    for (int c = 0; c < nc; ++c) {
        const size_t cbase = (size_t)(b * nc + c) * chunk_stride;
        float4 rp0, rp1, rp2, rp3;
        if (c + 1 < nc) {
            const float4* g = reinterpret_cast<const float4*>(Pb + cbase + chunk_stride);
            rp0 = g[tid]; rp1 = g[tid + 256]; rp2 = g[tid + 512]; rp3 = g[tid + 768];
        }
        float4 rq = *reinterpret_cast<const float4*>(Qb + cbase + (size_t)gr * 64 + j4);

        float ax = 0.f, ay = 0.f, az = 0.f, aw = 0.f;
        const float* Mrow = &sMl[cur * 1088 + rl * 68];
        const float* Pl = sP + (c & 1) * 4096;
#pragma unroll 4
        for (int mg = 0; mg < 16; ++mg) {
            float4 a4 = *reinterpret_cast<const float4*>(Mrow + mg * 4);
            float4 p0 = *reinterpret_cast<const float4*>(Pl + (mg * 4 + 0) * 64 + j4);
            float4 p1 = *reinterpret_cast<const float4*>(Pl + (mg * 4 + 1) * 64 + j4);
            float4 p2 = *reinterpret_cast<const float4*>(Pl + (mg * 4 + 2) * 64 + j4);
            float4 p3 = *reinterpret_cast<const float4*>(Pl + (mg * 4 + 3) * 64 + j4);
            ax = fmaf(a4.x, p0.x, ax); ay = fmaf(a4.x, p0.y, ay);
            az = fmaf(a4.x, p0.z, az); aw = fmaf(a4.x, p0.w, aw);
            ax = fmaf(a4.y, p1.x, ax); ay = fmaf(a4.y, p1.y, ay);
            az = fmaf(a4.y, p1.z, az); aw = fmaf(a4.y, p1.w, aw);
            ax = fmaf(a4.z, p2.x, ax); ay = fmaf(a4.z, p2.y, ay);
            az = fmaf(a4.z, p2.z, az); aw = fmaf(a4.z, p2.w, aw);
            ax = fmaf(a4.w, p3.x, ax); ay = fmaf(a4.w, p3.y, ay);
            az = fmaf(a4.w, p3.z, az); aw = fmaf(a4.w, p3.w, aw);
        }
        const int nxt = cur ^ 1;
        *reinterpret_cast<float4*>(&sMl[nxt * 1088 + rl * 68 + j4]) =
            make_float4(ax + rq.x, ay + rq.y, az + rq.z, aw + rq.w);
        if (c + 1 < nc) {
            float4* s = reinterpret_cast<float4*>(sP + ((c + 1) & 1) * 4096);
            s[tid] = rp0; s[tid + 256] = rp1; s[tid + 512] = rp2; s[tid + 768] = rp3;
        }
        __syncthreads();
        cur = nxt;
    }
    *reinterpret_cast<float4*>(Mout + ((size_t)b * 64 + gr) * 64 + j4) =
        *reinterpret_cast<const float4*>(&sMl[cur * 1088 + rl * 68 + j4]);

    // ---- fused precompute: last block of this batch runs it ----
    __threadfence();                          // make M rows visible device-wide
    __syncthreads();                          // all threads' stores issued
    if (tid == 0) {
        int old = atomicAdd(&cnt[b], 1);
        sWin = (old == 3) ? 1 : 0;
    }
    __syncthreads();
    if (!sWin) return;
    __threadfence();                          // acquire: other blocks' M visible

    float* pcM  = lds;                        // 64x68
    float* pcOp = lds + 4352;                 // 64x68
    const int jq = (tid & 15) * 4;
    const int tq = (tid >> 4) * 4;
    const float* Mb = Mout + (size_t)b * 4096;

    __syncthreads();                          // combine-phase LDS reads done
    stage_w_n(Mb, pcM, tid);
    stage_w_n(Wattn, pcOp, tid);
    __syncthreads();
    {
        float a[16];
        proj_tile64(pcM, pcOp, jq, tq, a);
#pragma unroll
        for (int v = 0; v < 4; ++v)
            *reinterpret_cast<float4*>(&WAM[(size_t)b * 4096 + (tq + v) * 64 + jq]) =
                make_float4(a[v], a[4 + v], a[8 + v], a[12 + v]);
    }
    __syncthreads();
    stage_w_t(Wk, 64, 0, pcOp, tid);
    __syncthreads();
    {
        float a[16];
        proj_tile64(pcM, pcOp, jq, tq, a);
#pragma unroll
        for (int v = 0; v < 4; ++v)
            *reinterpret_cast<float4*>(&MK[(size_t)b * 4096 + (tq + v) * 64 + jq]) =
                make_float4(a[v], a[4 + v], a[8 + v], a[12 + v]);
    }
    __syncthreads();
    stage_w_t(Wv, 64, 0, pcOp, tid);
    __syncthreads();
    {
        float a[16];
        proj_tile64(pcM, pcOp, jq, tq, a);
#pragma unroll
        for (int v = 0; v < 4; ++v)
            *reinterpret_cast<float4*>(&MV[(size_t)b * 4096 + (tq + v) * 64 + jq]) =
                make_float4(a[v], a[4 + v], a[8 + v], a[12 + v]);
    }
}

// ---------------------------------------------------------------------------
// Attention v5 (unchanged).
// ---------------------------------------------------------------------------
__global__ __launch_bounds__(256) void attn_kernel(
    const float* __restrict__ hidT, const float* __restrict__ WAM,
    const float* __restrict__ MK, const float* __restrict__ MV,
    float* __restrict__ ks2, float* __restrict__ vs2)
{
    __shared__ __align__(16) float sW1[64 * 68];
    __shared__ __align__(16) float sW2[64 * 68];
    __shared__ __align__(16) float sA[64 * 68];

    const int b = blockIdx.y;
    const int tile0 = blockIdx.x * 64;
    const int tid = threadIdx.x;
    const int jq = (tid & 15) * 4;
    const int tq = (tid >> 4) * 4;
    const size_t qbase = (size_t)b * 2048 + tile0;
    const float* hb = hidT + (size_t)b * 64 * 2048 + tile0;

    float4 pfk[4];
    stage_w_n(WAM + (size_t)b * 4096, sW1, tid);
    stage_w_t(MV + (size_t)b * 4096, 64, 0, sW2, tid);
#pragma unroll
    for (int it = 0; it < 4; ++it) {
        int item = it * 256 + tid;
        int i = item >> 4, q4 = (item & 15) * 4;
        float4 v = *reinterpret_cast<const float4*>(&hb[(size_t)i * 2048 + q4]);
        *reinterpret_cast<float4*>(&sA[i * 68 + q4]) = v;
    }
    load_w_t(MK + (size_t)b * 4096, 64, 0, tid, pfk);
    __syncthreads();                                       // (1)

    float a[16];
    proj_tile64(sW1, sA, jq, tq, a);
#pragma unroll
    for (int u = 0; u < 16; ++u) a[u] *= 0.125f;

    {
        float mx[4], sm[4];
#pragma unroll
        for (int v = 0; v < 4; ++v)
            mx[v] = fmaxf(fmaxf(a[v], a[4 + v]), fmaxf(a[8 + v], a[12 + v]));
#pragma unroll
        for (int m = 1; m <= 8; m <<= 1) {
#pragma unroll
            for (int v = 0; v < 4; ++v) mx[v] = fmaxf(mx[v], __shfl_xor(mx[v], m));
        }
#pragma unroll
        for (int v = 0; v < 4; ++v) {
            a[v]      = __expf(a[v]      - mx[v]);
            a[4 + v]  = __expf(a[4 + v]  - mx[v]);
            a[8 + v]  = __expf(a[8 + v]  - mx[v]);
            a[12 + v] = __expf(a[12 + v] - mx[v]);
            sm[v] = a[v] + a[4 + v] + a[8 + v] + a[12 + v];
        }
#pragma unroll
        for (int m = 1; m <= 8; m <<= 1) {
#pragma unroll
            for (int v = 0; v < 4; ++v) sm[v] += __shfl_xor(sm[v], m);
        }
        float rinv[4];
#pragma unroll
        for (int v = 0; v < 4; ++v) rinv[v] = 1.f / sm[v];
#pragma unroll
        for (int v = 0; v < 4; ++v) {
            a[v] *= rinv[v]; a[4 + v] *= rinv[v];
            a[8 + v] *= rinv[v]; a[12 + v] *= rinv[v];
        }
    }
    __syncthreads();                                       // (2)
#pragma unroll
    for (int u = 0; u < 4; ++u)
        *reinterpret_cast<float4*>(&sA[(jq + u) * 68 + tq]) =
            make_float4(a[u * 4 + 0], a[u * 4 + 1], a[u * 4 + 2], a[u * 4 + 3]);
    write_w_t(pfk, sW1, tid);
    __syncthreads();                                       // (3)

    float ak[16], av[16];
#pragma unroll
    for (int u = 0; u < 16; ++u) { ak[u] = 0.f; av[u] = 0.f; }
#pragma unroll 2
    for (int i = 0; i < 64; ++i) {
        float4 wk = *reinterpret_cast<const float4*>(&sW1[i * 68 + jq]);
        float4 wv = *reinterpret_cast<const float4*>(&sW2[i * 68 + jq]);
        float4 p4 = *reinterpret_cast<const float4*>(&sA[i * 68 + tq]);
        FMA16(ak, wk, p4);
        FMA16(av, wv, p4);
    }

    {
        float ssq[4];
#pragma unroll
        for (int v = 0; v < 4; ++v)
            ssq[v] = ak[v] * ak[v] + ak[4 + v] * ak[4 + v]
                   + ak[8 + v] * ak[8 + v] + ak[12 + v] * ak[12 + v];
#pragma unroll
        for (int m = 1; m <= 8; m <<= 1) {
#pragma unroll
            for (int v = 0; v < 4; ++v) ssq[v] += __shfl_xor(ssq[v], m);
        }
#pragma unroll
        for (int v = 0; v < 4; ++v) {
            float sc = 1.f / fmaxf(sqrtf(ssq[v]), 1e-12f);
            const size_t o = (qbase + tq + v) * 64 + jq;
            *reinterpret_cast<float4*>(&ks2[o]) =
                make_float4(ak[v] * sc, ak[4 + v] * sc, ak[8 + v] * sc, ak[12 + v] * sc);
            *reinterpret_cast<float4*>(&vs2[o]) =
                make_float4(av[v], av[4 + v], av[8 + v], av[12 + v]);
        }
    }
}

// ---------------------------------------------------------------------------
// Final kernel (unchanged from round 18): backward chunk-level vector pass.
// ---------------------------------------------------------------------------
__global__ __launch_bounds__(256) void final_kernel(
    const float* __restrict__ Pb, const float* __restrict__ Qb,
    const float* __restrict__ Mbuf, const float* __restrict__ qlast,
    const float* __restrict__ Wout, const float* __restrict__ bout,
    float* __restrict__ out, int nc, int chunk_stride)
{
    __shared__ float s[64], qv[64], rv[64];
    const int b = blockIdx.x;
    const int tid = threadIdx.x;
    const int r = tid >> 2;
    const int c0 = (tid & 3) * 16;

    if (tid < 64) { s[tid] = qlast[(size_t)b * 64 + tid]; qv[tid] = 0.f; }
    __syncthreads();

    for (int c = nc - 1; c >= 0; --c) {
        const size_t base = (size_t)(b * nc + c) * chunk_stride + (size_t)r * 64 + c0;
        const float4* gp = reinterpret_cast<const float4*>(Pb + base);
        const float4* gq = reinterpret_cast<const float4*>(Qb + base);
        float4 P0 = gp[0], P1 = gp[1], P2 = gp[2], P3 = gp[3];
        float4 Q0 = gq[0], Q1 = gq[1], Q2 = gq[2], Q3 = gq[3];
        const float4* sv4 = reinterpret_cast<const float4*>(&s[c0]);
        float4 s0 = sv4[0], s1 = sv4[1], s2 = sv4[2], s3 = sv4[3];

        float dp = 0.f, dq = 0.f;
        dp = fmaf(P0.x, s0.x, dp); dp = fmaf(P0.y, s0.y, dp);
        dp = fmaf(P0.z, s0.z, dp); dp = fmaf(P0.w, s0.w, dp);
        dp = fmaf(P1.x, s1.x, dp); dp = fmaf(P1.y, s1.y, dp);
        dp = fmaf(P1.z, s1.z, dp); dp = fmaf(P1.w, s1.w, dp);
        dp = fmaf(P2.x, s2.x, dp); dp = fmaf(P2.y, s2.y, dp);
        dp = fmaf(P2.z, s2.z, dp); dp = fmaf(P2.w, s2.w, dp);
        dp = fmaf(P3.x, s3.x, dp); dp = fmaf(P3.y, s3.y, dp);
        dp = fmaf(P3.z, s3.z, dp); dp = fmaf(P3.w, s3.w, dp);
        dq = fmaf(Q0.x, s0.x, dq); dq = fmaf(Q0.y, s0.y, dq);
        dq = fmaf(Q0.z, s0.z, dq); dq = fmaf(Q0.w, s0.w, dq);
        dq = fmaf(Q1.x, s1.x, dq); dq = fmaf(Q1.y, s1.y, dq);
        dq = fmaf(Q1.z, s1.z, dq); dq = fmaf(Q1.w, s1.w, dq);
        dq = fmaf(Q2.x, s2.x, dq); dq = fmaf(Q2.y, s2.y, dq);
        dq = fmaf(Q2.z, s2.z, dq); dq = fmaf(Q2.w, s2.w, dq);
        dq = fmaf(Q3.x, s3.x, dq); dq = fmaf(Q3.y, s3.y, dq);
        dq = fmaf(Q3.z, s3.z, dq); dq = fmaf(Q3.w, s3.w, dq);
        dp = dpp_xor1_add(dp); dp = dpp_xor2_add(dp);
        dq = dpp_xor1_add(dq); dq = dpp_xor2_add(dq);

        __syncthreads();
        if ((tid & 3) == 0) { s[r] = dp; qv[r] += dq; }
        __syncthreads();
    }

    {
        const float4* gm = reinterpret_cast<const float4*>(
            Mbuf + (size_t)b * 4096 + (size_t)r * 64 + c0);
        float4 M0 = gm[0], M1 = gm[1], M2v = gm[2], M3 = gm[3];
        const float4* sv4 = reinterpret_cast<const float4*>(&s[c0]);
        float4 s0 = sv4[0], s1 = sv4[1], s2 = sv4[2], s3 = sv4[3];
        float d = 0.f;
        d = fmaf(M0.x, s0.x, d); d = fmaf(M0.y, s0.y, d);
        d = fmaf(M0.z, s0.z, d); d = fmaf(M0.w, s0.w, d);
        d = fmaf(M1.x, s1.x, d); d = fmaf(M1.y, s1.y, d);
        d = fmaf(M1.z, s1.z, d); d = fmaf(M1.w, s1.w, d);
        d = fmaf(M2v.x, s2.x, d); d = fmaf(M2v.y, s2.y, d);
        d = fmaf(M2v.z, s2.z, d); d = fmaf(M2v.w, s2.w, d);
        d = fmaf(M3.x, s3.x, d); d = fmaf(M3.y, s3.y, d);
        d = fmaf(M3.z, s3.z, d); d = fmaf(M3.w, s3.w, d);
        d = dpp_xor1_add(d); d = dpp_xor2_add(d);
        if ((tid & 3) == 0) rv[r] = d + qv[r];
    }
    __syncthreads();

    if (tid < 128) {
        const float* wr = Wout + (size_t)tid * 64;
        float a0 = 0.f, a1 = 0.f, a2 = 0.f, a3 = 0.f;
#pragma unroll
        for (int h = 0; h < 64; h += 4) {
            a0 = fmaf(wr[h],     rv[h],     a0);
            a1 = fmaf(wr[h + 1], rv[h + 1], a1);
            a2 = fmaf(wr[h + 2], rv[h + 2], a2);
            a3 = fmaf(wr[h + 3], rv[h + 3], a3);
        }
        out[(size_t)b * 128 + tid] = bout[tid] + (a0 + a1) + (a2 + a3);
    }
}

// ---------------------------------------------------------------------------
extern "C" void kernel_launch(void* const* d_in, const int* in_sizes, int n_in,
                              void* d_out, int out_size, void* d_ws, size_t ws_size,
                              hipStream_t stream)
{
    const int* x        = (const int*)d_in[0];
    const float* embed  = (const float*)d_in[1];
    const float* W1     = (const float*)d_in[2];
    const float* b1     = (const float*)d_in[3];
    const float* W2     = (const float*)d_in[4];
    const float* b2     = (const float*)d_in[5];
    const float* ln_g   = (const float*)d_in[6];
    const float* ln_b   = (const float*)d_in[7];
    const float* Wk     = (const float*)d_in[8];
    const float* Wv     = (const float*)d_in[9];
    const float* Wq     = (const float*)d_in[10];
    const float* Wattn  = (const float*)d_in[11];
    const float* Wout   = (const float*)d_in[12];
    const float* bout   = (const float*)d_in[13];

    // workspace (floats): ks | vs | hidT | qlast | M | WAM | MK | MV | cnt
    float* ws = (float*)d_ws;
    float* ks  = ws;
    float* vs  = ks  + (size_t)NB * SEQL * 64;
    float* hid = vs  + (size_t)NB * SEQL * 64;
    float* ql  = hid + (size_t)NB * 2048 * 64;
    float* M   = ql  + (size_t)NB * 64;
    float* WAM = M   + (size_t)NB * 64 * 64;
    float* MK  = WAM + (size_t)NB * 64 * 64;
    float* MV  = MK  + (size_t)NB * 64 * 64;
    int*   cnt = (int*)(MV + (size_t)NB * 64 * 64);
    if (ws_size < ((size_t)(MV + (size_t)NB * 64 * 64 - ws) + NB) * sizeof(float)) return;

    hipLaunchKernelGGL(encoder_kernel, dim3((NB * SEQL) / 64), dim3(256), 0, stream,
                       x, embed, W1, b1, W2, b2, ln_g, ln_b, Wk, Wv, Wq,
                       ks, vs, hid, ql);

    // scan 1: L=4096, C=256 -> 16 chunks/batch; chunk1 also zeroes cnt[0..63]
    const int C1 = 256, nc1 = SEQL / C1;
    hipLaunchKernelGGL(chunk_kernel, dim3(NB * nc1), dim3(256), 0, stream, ks, vs, C1, cnt);
    hipLaunchKernelGGL(combine_kernel, dim3(NB * 4), dim3(256), 0, stream,
                       ks, vs, M, nc1, C1 * 64,
                       Wattn, Wk, Wv, WAM, MK, MV, cnt);

    // attention + second k/v projection (ks2/vs2 reuse ks/vs)
    hipLaunchKernelGGL(attn_kernel, dim3(32, NB), dim3(256), 0, stream,
                       hid, WAM, MK, MV, ks, vs);

    // scan 2: L=2048, C=128 -> 16 chunks/batch; final = backward vector pass
    const int C2 = 128, nc2 = 2048 / C2;
    hipLaunchKernelGGL(chunk_kernel, dim3(NB * nc2), dim3(256), 0, stream, ks, vs, C2, cnt);
    hipLaunchKernelGGL(final_kernel, dim3(NB), dim3(256), 0, stream,
                       ks, vs, M, ql, Wout, bout, (float*)d_out, nc2, C2 * 64);
}

// Round 20
// 467.451 us; speedup vs baseline: 1.0732x; 1.0732x over previous
//
#include <hip/hip_runtime.h>

#define SEQL 4096
#define NB 64

// ---------------------------------------------------------------------------
// DPP quad-reductions (VALU pipe, no DS ops).
// ---------------------------------------------------------------------------
__device__ __forceinline__ float dpp_xor1_add(float x) {
    int v = __builtin_amdgcn_mov_dpp(__float_as_int(x), 0xB1, 0xF, 0xF, true);
    return x + __int_as_float(v);
}
__device__ __forceinline__ float dpp_xor2_add(float x) {
    int v = __builtin_amdgcn_mov_dpp(__float_as_int(x), 0x4E, 0xF, 0xF, true);
    return x + __int_as_float(v);
}

// ---------------------------------------------------------------------------
// Shared helpers: 4x4-tile GEMM on 64x68 LDS buffers.
// ---------------------------------------------------------------------------
#define FMA16(A, W, H)                                      \
    A[0]  = fmaf(W.x, H.x, A[0]);  A[1]  = fmaf(W.x, H.y, A[1]);   \
    A[2]  = fmaf(W.x, H.z, A[2]);  A[3]  = fmaf(W.x, H.w, A[3]);   \
    A[4]  = fmaf(W.y, H.x, A[4]);  A[5]  = fmaf(W.y, H.y, A[5]);   \
    A[6]  = fmaf(W.y, H.z, A[6]);  A[7]  = fmaf(W.y, H.w, A[7]);   \
    A[8]  = fmaf(W.z, H.x, A[8]);  A[9]  = fmaf(W.z, H.y, A[9]);   \
    A[10] = fmaf(W.z, H.z, A[10]); A[11] = fmaf(W.z, H.w, A[11]);  \
    A[12] = fmaf(W.w, H.x, A[12]); A[13] = fmaf(W.w, H.y, A[13]);  \
    A[14] = fmaf(W.w, H.z, A[14]); A[15] = fmaf(W.w, H.w, A[15])

__device__ __forceinline__ void proj_tile64(const float* __restrict__ sW,
                                            const float* __restrict__ sA,
                                            int jq, int tq, float* __restrict__ a)
{
#pragma unroll
    for (int u = 0; u < 16; ++u) a[u] = 0.f;
#pragma unroll 4
    for (int i = 0; i < 64; ++i) {
        float4 w  = *reinterpret_cast<const float4*>(&sW[i * 68 + jq]);
        float4 h4 = *reinterpret_cast<const float4*>(&sA[i * 68 + tq]);
        FMA16(a, w, h4);
    }
}

// transposed weight stage, split into load (regs) and write (LDS) halves.
__device__ __forceinline__ void load_w_t(const float* __restrict__ W, int ldw, int col0,
                                         int tid, float4* __restrict__ r)
{
    const int j = tid & 63;
    const int cq0 = tid >> 6;
#pragma unroll
    for (int it = 0; it < 4; ++it)
        r[it] = *reinterpret_cast<const float4*>(&W[(size_t)j * ldw + col0 + (it * 4 + cq0) * 4]);
}
__device__ __forceinline__ void write_w_t(const float4* __restrict__ r,
                                          float* __restrict__ sWb, int tid)
{
    const int j = tid & 63;
    const int cq0 = tid >> 6;
#pragma unroll
    for (int it = 0; it < 4; ++it) {
        const int c = (it * 4 + cq0) * 4;
        sWb[(c + 0) * 68 + j] = r[it].x;
        sWb[(c + 1) * 68 + j] = r[it].y;
        sWb[(c + 2) * 68 + j] = r[it].z;
        sWb[(c + 3) * 68 + j] = r[it].w;
    }
}

__device__ __forceinline__ void stage_w_t(const float* __restrict__ W, int ldw, int col0,
                                          float* __restrict__ sWb, int tid)
{
    float4 r[4];
    load_w_t(W, ldw, col0, tid, r);
    write_w_t(r, sWb, tid);
}
__device__ __forceinline__ void stage_w_n(const float* __restrict__ W,
                                          float* __restrict__ sWb, int tid)
{
#pragma unroll
    for (int it = 0; it < 4; ++it) {
        int item = it * 256 + tid;
        int r = item >> 4, c4 = item & 15;
        float4 w = *reinterpret_cast<const float4*>(&W[(size_t)r * 64 + c4 * 4]);
        *reinterpret_cast<float4*>(&sWb[r * 68 + c4 * 4]) = w;
    }
}

// ---------------------------------------------------------------------------
// Encoder v6.
// ---------------------------------------------------------------------------
__global__ __launch_bounds__(256) void encoder_kernel(
    const int* __restrict__ x, const float* __restrict__ embed,
    const float* __restrict__ W1, const float* __restrict__ b1,
    const float* __restrict__ W2, const float* __restrict__ b2,
    const float* __restrict__ ln_g, const float* __restrict__ ln_b,
    const float* __restrict__ Wk, const float* __restrict__ Wv,
    const float* __restrict__ Wq,
    float* __restrict__ ks, float* __restrict__ vs,
    float* __restrict__ hidT, float* __restrict__ qlast)
{
    __shared__ __align__(16) float sZ[64 * 68];
    __shared__ __align__(16) float sF[64 * 68];
    __shared__ __align__(16) float sW[64 * 68];

    const int tid = threadIdx.x;
    const size_t g0 = (size_t)blockIdx.x * 64;
    const int b = (int)(g0 >> 12);
    const int l0 = (int)(g0 & (SEQL - 1));
    const int jq = (tid & 15) * 4;
    const int tq = (tid >> 4) * 4;
    const bool doq = (l0 < 2048);
    const bool dolast = (l0 == SEQL - 64);

    float4 pf[4], pf2[4];

    load_w_t(W1, 64, 0, tid, pf);
    for (int idx = tid; idx < 4096; idx += 256) {
        int t = idx >> 6, i = idx & 63;
        sZ[i * 68 + t] = embed[(size_t)x[g0 + t] * 64 + i];
    }
    write_w_t(pf, sW, tid);
    load_w_t(W2, 128, 0, tid, pf2);
    __syncthreads();                                   // (1)

    float zacc[16];
#pragma unroll
    for (int u = 0; u < 16; ++u) zacc[u] = 0.f;

    {
        float a[16];
        proj_tile64(sW, sZ, jq, tq, a);
        float4 bb = *reinterpret_cast<const float4*>(&b1[jq]);
        float bv[4] = {bb.x, bb.y, bb.z, bb.w};
#pragma unroll
        for (int u = 0; u < 4; ++u) {
            float4 o;
            o.x = fmaxf(a[u * 4 + 0] + bv[u], 0.f);
            o.y = fmaxf(a[u * 4 + 1] + bv[u], 0.f);
            o.z = fmaxf(a[u * 4 + 2] + bv[u], 0.f);
            o.w = fmaxf(a[u * 4 + 3] + bv[u], 0.f);
            *reinterpret_cast<float4*>(&sF[(jq + u) * 68 + tq]) = o;
        }
    }
    __syncthreads();                                   // (2)
    write_w_t(pf2, sW, tid);
    load_w_t(W1 + 4096, 64, 0, tid, pf);
    __syncthreads();                                   // (3)
#pragma unroll 4
    for (int p = 0; p < 64; ++p) {
        float4 w  = *reinterpret_cast<const float4*>(&sW[p * 68 + jq]);
        float4 f4 = *reinterpret_cast<const float4*>(&sF[p * 68 + tq]);
        FMA16(zacc, w, f4);
    }
    __syncthreads();                                   // (4)
    write_w_t(pf, sW, tid);
    load_w_t(W2, 128, 64, tid, pf2);
    __syncthreads();                                   // (5)
    {
        float a[16];
        proj_tile64(sW, sZ, jq, tq, a);
        float4 bb = *reinterpret_cast<const float4*>(&b1[64 + jq]);
        float bv[4] = {bb.x, bb.y, bb.z, bb.w};
#pragma unroll
        for (int u = 0; u < 4; ++u) {
            float4 o;
            o.x = fmaxf(a[u * 4 + 0] + bv[u], 0.f);
            o.y = fmaxf(a[u * 4 + 1] + bv[u], 0.f);
            o.z = fmaxf(a[u * 4 + 2] + bv[u], 0.f);
            o.w = fmaxf(a[u * 4 + 3] + bv[u], 0.f);
            *reinterpret_cast<float4*>(&sF[(jq + u) * 68 + tq]) = o;
        }
    }
    __syncthreads();                                   // (6)
    write_w_t(pf2, sW, tid);
    load_w_t(Wk, 64, 0, tid, pf);
    load_w_t(Wv, 64, 0, tid, pf2);
    __syncthreads();                                   // (7)
#pragma unroll 4
    for (int p = 0; p < 64; ++p) {
        float4 w  = *reinterpret_cast<const float4*>(&sW[p * 68 + jq]);
        float4 f4 = *reinterpret_cast<const float4*>(&sF[p * 68 + tq]);
        FMA16(zacc, w, f4);
    }

    {
        float z[16];
        float4 b2v = *reinterpret_cast<const float4*>(&b2[jq]);
        float bv[4] = {b2v.x, b2v.y, b2v.z, b2v.w};
#pragma unroll
        for (int u = 0; u < 4; ++u) {
            float4 h4 = *reinterpret_cast<const float4*>(&sZ[(jq + u) * 68 + tq]);
            z[u * 4 + 0] = h4.x + bv[u] + zacc[u * 4 + 0];
            z[u * 4 + 1] = h4.y + bv[u] + zacc[u * 4 + 1];
            z[u * 4 + 2] = h4.z + bv[u] + zacc[u * 4 + 2];
            z[u * 4 + 3] = h4.w + bv[u] + zacc[u * 4 + 3];
        }
        float s[4], ss[4];
#pragma unroll
        for (int v = 0; v < 4; ++v) {
            s[v]  = z[v] + z[4 + v] + z[8 + v] + z[12 + v];
            ss[v] = z[v] * z[v] + z[4 + v] * z[4 + v]
                  + z[8 + v] * z[8 + v] + z[12 + v] * z[12 + v];
        }
#pragma unroll
        for (int m = 1; m <= 8; m <<= 1) {
#pragma unroll
            for (int v = 0; v < 4; ++v) {
                s[v]  += __shfl_xor(s[v], m);
                ss[v] += __shfl_xor(ss[v], m);
            }
        }
        float mu[4], inv[4];
#pragma unroll
        for (int v = 0; v < 4; ++v) {
            mu[v] = s[v] * 0.015625f;
            float var = ss[v] * 0.015625f - mu[v] * mu[v];
            inv[v] = rsqrtf(var + 1e-5f);
        }
        float4 g4  = *reinterpret_cast<const float4*>(&ln_g[jq]);
        float4 be4 = *reinterpret_cast<const float4*>(&ln_b[jq]);
        float gv[4] = {g4.x, g4.y, g4.z, g4.w};
        float bev[4] = {be4.x, be4.y, be4.z, be4.w};
#pragma unroll
        for (int u = 0; u < 4; ++u) {
            float4 o;
            o.x = (z[u * 4 + 0] - mu[0]) * inv[0] * gv[u] + bev[u];
            o.y = (z[u * 4 + 1] - mu[1]) * inv[1] * gv[u] + bev[u];
            o.z = (z[u * 4 + 2] - mu[2]) * inv[2] * gv[u] + bev[u];
            o.w = (z[u * 4 + 3] - mu[3]) * inv[3] * gv[u] + bev[u];
            *reinterpret_cast<float4*>(&sZ[(jq + u) * 68 + tq]) = o;
        }
    }
    __syncthreads();                                   // (8)
    write_w_t(pf, sW, tid);                            // sW = Wk
    write_w_t(pf2, sF, tid);                           // sF = Wv
    if (dolast) load_w_t(Wq, 64, 0, tid, pf);
    __syncthreads();                                   // (9)

    // k projection + l2norm
    {
        float a[16];
        proj_tile64(sW, sZ, jq, tq, a);
        float ssq[4];
#pragma unroll
        for (int v = 0; v < 4; ++v)
            ssq[v] = a[v] * a[v] + a[4 + v] * a[4 + v]
                   + a[8 + v] * a[8 + v] + a[12 + v] * a[12 + v];
#pragma unroll
        for (int m = 1; m <= 8; m <<= 1) {
#pragma unroll
            for (int v = 0; v < 4; ++v) ssq[v] += __shfl_xor(ssq[v], m);
        }
#pragma unroll
        for (int v = 0; v < 4; ++v) {
            float sc = 1.f / fmaxf(sqrtf(ssq[v]), 1e-12f);
            float4 o = make_float4(a[v] * sc, a[4 + v] * sc, a[8 + v] * sc, a[12 + v] * sc);
            *reinterpret_cast<float4*>(&ks[(g0 + tq + v) * 64 + jq]) = o;
        }
    }
    // v projection
    {
        float a[16];
        proj_tile64(sF, sZ, jq, tq, a);
#pragma unroll
        for (int v = 0; v < 4; ++v) {
            float4 o = make_float4(a[v], a[4 + v], a[8 + v], a[12 + v]);
            *reinterpret_cast<float4*>(&vs[(g0 + tq + v) * 64 + jq]) = o;
        }
    }

    // hidden -> hidT (channel-major [b][i][l]; coalesced float4 rows)
    if (doq) {
#pragma unroll
        for (int it = 0; it < 4; ++it) {
            int item = it * 256 + tid;
            int i = item >> 4, q4 = (item & 15) * 4;
            float4 v = *reinterpret_cast<const float4*>(&sZ[i * 68 + q4]);
            *reinterpret_cast<float4*>(&hidT[((size_t)b * 64 + i) * 2048 + l0 + q4]) = v;
        }
    }

    if (dolast) {
        __syncthreads();                               // (10)
        write_w_t(pf, sW, tid);
        __syncthreads();                               // (11)
        float a[16];
        proj_tile64(sW, sZ, jq, tq, a);
        if ((tid >> 4) == 15) {
            float4 o = make_float4(a[3], a[7], a[11], a[15]);
            *reinterpret_cast<float4*>(&qlast[(size_t)b * 64 + jq]) = o;
        }
    }
}

// ---------------------------------------------------------------------------
// Per-batch precompute: WAM = Wattn^T M, MK = Wk M, MV = Wv M.
// ---------------------------------------------------------------------------
__global__ __launch_bounds__(256) void precompute_kernel(
    const float* __restrict__ Mbuf, const float* __restrict__ Wattn,
    const float* __restrict__ Wk, const float* __restrict__ Wv,
    float* __restrict__ WAM, float* __restrict__ MK, float* __restrict__ MV)
{
    __shared__ __align__(16) float sM[64 * 68];
    __shared__ __align__(16) float sOp[64 * 68];
    const int b = blockIdx.x;
    const int tid = threadIdx.x;
    const int jq = (tid & 15) * 4;
    const int tq = (tid >> 4) * 4;
    const float* Mb = Mbuf + (size_t)b * 4096;

    stage_w_n(Mb, sM, tid);
    stage_w_n(Wattn, sOp, tid);
    __syncthreads();
    {
        float a[16];
        proj_tile64(sM, sOp, jq, tq, a);
#pragma unroll
        for (int v = 0; v < 4; ++v)
            *reinterpret_cast<float4*>(&WAM[(size_t)b * 4096 + (tq + v) * 64 + jq]) =
                make_float4(a[v], a[4 + v], a[8 + v], a[12 + v]);
    }
    __syncthreads();
    stage_w_t(Wk, 64, 0, sOp, tid);
    __syncthreads();
    {
        float a[16];
        proj_tile64(sM, sOp, jq, tq, a);
#pragma unroll
        for (int v = 0; v < 4; ++v)
            *reinterpret_cast<float4*>(&MK[(size_t)b * 4096 + (tq + v) * 64 + jq]) =
                make_float4(a[v], a[4 + v], a[8 + v], a[12 + v]);
    }
    __syncthreads();
    stage_w_t(Wv, 64, 0, sOp, tid);
    __syncthreads();
    {
        float a[16];
        proj_tile64(sM, sOp, jq, tq, a);
#pragma unroll
        for (int v = 0; v < 4; ++v)
            *reinterpret_cast<float4*>(&MV[(size_t)b * 4096 + (tq + v) * 64 + jq]) =
                make_float4(a[v], a[4 + v], a[8 + v], a[12 + v]);
    }
}

// ---------------------------------------------------------------------------
// Chunked delta scan, phase A (round-11 known-good version).
// ---------------------------------------------------------------------------
#define STEP2(K0, K1, K2, K3, V)                                                \
    do {                                                                        \
        float dp0 = fmaf(p[0], K0.x, fmaf(p[1], K0.y, fmaf(p[2], K0.z, p[3] * K0.w))); \
        float dp1 = fmaf(p[4], K1.x, fmaf(p[5], K1.y, fmaf(p[6], K1.z, p[7] * K1.w))); \
        float dp2 = fmaf(p[8], K2.x, fmaf(p[9], K2.y, fmaf(p[10], K2.z, p[11] * K2.w))); \
        float dp3 = fmaf(p[12], K3.x, fmaf(p[13], K3.y, fmaf(p[14], K3.z, p[15] * K3.w))); \
        float dq0 = fmaf(q[0], K0.x, fmaf(q[1], K0.y, fmaf(q[2], K0.z, q[3] * K0.w))); \
        float dq1 = fmaf(q[4], K1.x, fmaf(q[5], K1.y, fmaf(q[6], K1.z, q[7] * K1.w))); \
        float dq2 = fmaf(q[8], K2.x, fmaf(q[9], K2.y, fmaf(q[10], K2.z, q[11] * K2.w))); \
        float dq3 = fmaf(q[12], K3.x, fmaf(q[13], K3.y, fmaf(q[14], K3.z, q[15] * K3.w))); \
        float ddp = (dp0 + dp1) + (dp2 + dp3);                                  \
        float ddq = (dq0 + dq1) + (dq2 + dq3);                                  \
        ddp = dpp_xor1_add(ddp);  ddq = dpp_xor1_add(ddq);                      \
        ddp = dpp_xor2_add(ddp);  ddq = dpp_xor2_add(ddq);                      \
        float up = -ddp;                                                        \
        float uq = V - ddq;                                                     \
        p[0] = fmaf(up, K0.x, p[0]);   q[0] = fmaf(uq, K0.x, q[0]);             \
        p[1] = fmaf(up, K0.y, p[1]);   q[1] = fmaf(uq, K0.y, q[1]);             \
        p[2] = fmaf(up, K0.z, p[2]);   q[2] = fmaf(uq, K0.z, q[2]);             \
        p[3] = fmaf(up, K0.w, p[3]);   q[3] = fmaf(uq, K0.w, q[3]);             \
        p[4] = fmaf(up, K1.x, p[4]);   q[4] = fmaf(uq, K1.x, q[4]);             \
        p[5] = fmaf(up, K1.y, p[5]);   q[5] = fmaf(uq, K1.y, q[5]);             \
        p[6] = fmaf(up, K1.z, p[6]);   q[6] = fmaf(uq, K1.z, q[6]);             \
        p[7] = fmaf(up, K1.w, p[7]);   q[7] = fmaf(uq, K1.w, q[7]);             \
        p[8] = fmaf(up, K2.x, p[8]);   q[8] = fmaf(uq, K2.x, q[8]);             \
        p[9] = fmaf(up, K2.y, p[9]);   q[9] = fmaf(uq, K2.y, q[9]);             \
        p[10] = fmaf(up, K2.z, p[10]); q[10] = fmaf(uq, K2.z, q[10]);           \
        p[11] = fmaf(up, K2.w, p[11]); q[11] = fmaf(uq, K2.w, q[11]);           \
        p[12] = fmaf(up, K3.x, p[12]); q[12] = fmaf(uq, K3.x, q[12]);           \
        p[13] = fmaf(up, K3.y, p[13]); q[13] = fmaf(uq, K3.y, q[13]);           \
        p[14] = fmaf(up, K3.z, p[14]); q[14] = fmaf(uq, K3.z, q[14]);           \
        p[15] = fmaf(up, K3.w, p[15]); q[15] = fmaf(uq, K3.w, q[15]);           \
    } while (0)

__global__ __launch_bounds__(256) void chunk_kernel(
    float* __restrict__ ksb, float* __restrict__ vsb, int C)
{
    __shared__ __align__(16) float sk[2][32 * 64];
    __shared__ __align__(16) float sv[2][32 * 64];

    const int job = blockIdx.x;
    const int tid = threadIdx.x;
    const int r = tid >> 2;
    const int c0 = (tid & 3) * 16;
    float* kc = ksb + (size_t)job * C * 64;
    float* vc = vsb + (size_t)job * C * 64;

    float p[16], q[16];
#pragma unroll
    for (int j = 0; j < 16; ++j) { p[j] = (c0 + j == r) ? 1.f : 0.f; q[j] = 0.f; }

    const int nt = C >> 5;
    float4 rk0, rk1, rv0, rv1;

    {
        const float4* gk = reinterpret_cast<const float4*>(kc);
        const float4* gv = reinterpret_cast<const float4*>(vc);
        float4 a0 = gk[tid], a1 = gk[256 + tid];
        float4 b0 = gv[tid], b1 = gv[256 + tid];
        float4* dk = reinterpret_cast<float4*>(sk[0]);
        float4* dv = reinterpret_cast<float4*>(sv[0]);
        dk[tid] = a0; dk[256 + tid] = a1;
        dv[tid] = b0; dv[256 + tid] = b1;
    }
    if (nt > 1) {
        const float4* gk = reinterpret_cast<const float4*>(kc + 2048);
        const float4* gv = reinterpret_cast<const float4*>(vc + 2048);
        rk0 = gk[tid]; rk1 = gk[256 + tid];
        rv0 = gv[tid]; rv1 = gv[256 + tid];
    }
    __syncthreads();

    int cur = 0;
    for (int tile = 0; tile < nt; ++tile) {
        if (tile + 1 < nt) {
            float4* dk = reinterpret_cast<float4*>(sk[cur ^ 1]);
            float4* dv = reinterpret_cast<float4*>(sv[cur ^ 1]);
            dk[tid] = rk0; dk[256 + tid] = rk1;
            dv[tid] = rv0; dv[256 + tid] = rv1;
            if (tile + 2 < nt) {
                const float4* gk = reinterpret_cast<const float4*>(kc + (size_t)(tile + 2) * 2048);
                const float4* gv = reinterpret_cast<const float4*>(vc + (size_t)(tile + 2) * 2048);
                rk0 = gk[tid]; rk1 = gk[256 + tid];
                rv0 = gv[tid]; rv1 = gv[256 + tid];
            }
        }

        const float* kl = sk[cur] + c0;
        const float* vl = sv[cur] + r;
        float4 a0, a1, a2, a3, e0, e1, e2, e3;
        float va, ve;
        {
            const float4* kp = reinterpret_cast<const float4*>(kl);
            a0 = kp[0]; a1 = kp[1]; a2 = kp[2]; a3 = kp[3];
            va = vl[0];
        }
#pragma unroll
        for (int t = 0; t < 32; t += 2) {
            {
                const float4* kp = reinterpret_cast<const float4*>(kl + (t + 1) * 64);
                e0 = kp[0]; e1 = kp[1]; e2 = kp[2]; e3 = kp[3];
                ve = vl[(t + 1) * 64];
            }
            STEP2(a0, a1, a2, a3, va);
            if (t + 2 < 32) {
                const float4* kp = reinterpret_cast<const float4*>(kl + (t + 2) * 64);
                a0 = kp[0]; a1 = kp[1]; a2 = kp[2]; a3 = kp[3];
                va = vl[(t + 2) * 64];
            }
            STEP2(e0, e1, e2, e3, ve);
        }
        __syncthreads();
        cur ^= 1;
    }

    float4* po = reinterpret_cast<float4*>(kc + r * 64 + c0);
    po[0] = make_float4(p[0], p[1], p[2], p[3]);
    po[1] = make_float4(p[4], p[5], p[6], p[7]);
    po[2] = make_float4(p[8], p[9], p[10], p[11]);
    po[3] = make_float4(p[12], p[13], p[14], p[15]);
    float4* qo = reinterpret_cast<float4*>(vc + r * 64 + c0);
    qo[0] = make_float4(q[0], q[1], q[2], q[3]);
    qo[1] = make_float4(q[4], q[5], q[6], q[7]);
    qo[2] = make_float4(q[8], q[9], q[10], q[11]);
    qo[3] = make_float4(q[12], q[13], q[14], q[15]);
}

// ---------------------------------------------------------------------------
// Chunked delta scan, phase B (row-split x4) — scan 1 only.
// ---------------------------------------------------------------------------
__global__ __launch_bounds__(256) void combine_kernel(
    const float* __restrict__ Pb, const float* __restrict__ Qb,
    const float* __restrict__ Min, float* __restrict__ Mout,
    int nc, int chunk_stride)
{
    __shared__ __align__(16) float sP[2][64 * 64];
    __shared__ __align__(16) float sM[2][16 * 68];
    const int bb = blockIdx.x;
    const int b = bb >> 2;
    const int r0 = (bb & 3) << 4;
    const int tid = threadIdx.x;
    const int rl = tid >> 4;
    const int j4 = (tid & 15) * 4;
    const int gr = r0 + rl;

    if (Min) {
        *reinterpret_cast<float4*>(&sM[0][rl * 68 + j4]) =
            *reinterpret_cast<const float4*>(Min + ((size_t)b * 64 + gr) * 64 + j4);
    } else {
        *reinterpret_cast<float4*>(&sM[0][rl * 68 + j4]) = make_float4(0.f, 0.f, 0.f, 0.f);
    }
    {
        const float4* g = reinterpret_cast<const float4*>(Pb + (size_t)b * nc * chunk_stride);
        float4* s = reinterpret_cast<float4*>(sP[0]);
        for (int i = tid; i < 1024; i += 256) s[i] = g[i];
    }
    __syncthreads();

    int cur = 0;
    for (int c = 0; c < nc; ++c) {
        const size_t cbase = (size_t)(b * nc + c) * chunk_stride;
        float4 rp0, rp1, rp2, rp3;
        if (c + 1 < nc) {
            const float4* g = reinterpret_cast<const float4*>(Pb + cbase + chunk_stride);
            rp0 = g[tid]; rp1 = g[tid + 256]; rp2 = g[tid + 512]; rp3 = g[tid + 768];
        }
        float4 rq = *reinterpret_cast<const float4*>(Qb + cbase + (size_t)gr * 64 + j4);

        float ax = 0.f, ay = 0.f, az = 0.f, aw = 0.f;
        const float* Mrow = &sM[cur][rl * 68];
        const float* Pl = sP[c & 1];
#pragma unroll 4
        for (int mg = 0; mg < 16; ++mg) {
            float4 a4 = *reinterpret_cast<const float4*>(Mrow + mg * 4);
            float4 p0 = *reinterpret_cast<const float4*>(Pl + (mg * 4 + 0) * 64 + j4);
            float4 p1 = *reinterpret_cast<const float4*>(Pl + (mg * 4 + 1) * 64 + j4);
            float4 p2 = *reinterpret_cast<const float4*>(Pl + (mg * 4 + 2) * 64 + j4);
            float4 p3 = *reinterpret_cast<const float4*>(Pl + (mg * 4 + 3) * 64 + j4);
            ax = fmaf(a4.x, p0.x, ax); ay = fmaf(a4.x, p0.y, ay);
            az = fmaf(a4.x, p0.z, az); aw = fmaf(a4.x, p0.w, aw);
            ax = fmaf(a4.y, p1.x, ax); ay = fmaf(a4.y, p1.y, ay);
            az = fmaf(a4.y, p1.z, az); aw = fmaf(a4.y, p1.w, aw);
            ax = fmaf(a4.z, p2.x, ax); ay = fmaf(a4.z, p2.y, ay);
            az = fmaf(a4.z, p2.z, az); aw = fmaf(a4.z, p2.w, aw);
            ax = fmaf(a4.w, p3.x, ax); ay = fmaf(a4.w, p3.y, ay);
            az = fmaf(a4.w, p3.z, az); aw = fmaf(a4.w, p3.w, aw);
        }
        const int nxt = cur ^ 1;
        *reinterpret_cast<float4*>(&sM[nxt][rl * 68 + j4]) =
            make_float4(ax + rq.x, ay + rq.y, az + rq.z, aw + rq.w);
        if (c + 1 < nc) {
            float4* s = reinterpret_cast<float4*>(sP[(c + 1) & 1]);
            s[tid] = rp0; s[tid + 256] = rp1; s[tid + 512] = rp2; s[tid + 768] = rp3;
        }
        __syncthreads();
        cur = nxt;
    }
    *reinterpret_cast<float4*>(Mout + ((size_t)b * 64 + gr) * 64 + j4) =
        *reinterpret_cast<const float4*>(&sM[cur][rl * 68 + j4]);
}

// ---------------------------------------------------------------------------
// Attention v5.
// ---------------------------------------------------------------------------
__global__ __launch_bounds__(256) void attn_kernel(
    const float* __restrict__ hidT, const float* __restrict__ WAM,
    const float* __restrict__ MK, const float* __restrict__ MV,
    float* __restrict__ ks2, float* __restrict__ vs2)
{
    __shared__ __align__(16) float sW1[64 * 68];
    __shared__ __align__(16) float sW2[64 * 68];
    __shared__ __align__(16) float sA[64 * 68];

    const int b = blockIdx.y;
    const int tile0 = blockIdx.x * 64;
    const int tid = threadIdx.x;
    const int jq = (tid & 15) * 4;
    const int tq = (tid >> 4) * 4;
    const size_t qbase = (size_t)b * 2048 + tile0;
    const float* hb = hidT + (size_t)b * 64 * 2048 + tile0;

    float4 pfk[4];
    stage_w_n(WAM + (size_t)b * 4096, sW1, tid);
    stage_w_t(MV + (size_t)b * 4096, 64, 0, sW2, tid);
#pragma unroll
    for (int it = 0; it < 4; ++it) {
        int item = it * 256 + tid;
        int i = item >> 4, q4 = (item & 15) * 4;
        float4 v = *reinterpret_cast<const float4*>(&hb[(size_t)i * 2048 + q4]);
        *reinterpret_cast<float4*>(&sA[i * 68 + q4]) = v;
    }
    load_w_t(MK + (size_t)b * 4096, 64, 0, tid, pfk);
    __syncthreads();                                       // (1)

    float a[16];
    proj_tile64(sW1, sA, jq, tq, a);
#pragma unroll
    for (int u = 0; u < 16; ++u) a[u] *= 0.125f;

    {
        float mx[4], sm[4];
#pragma unroll
        for (int v = 0; v < 4; ++v)
            mx[v] = fmaxf(fmaxf(a[v], a[4 + v]), fmaxf(a[8 + v], a[12 + v]));
#pragma unroll
        for (int m = 1; m <= 8; m <<= 1) {
#pragma unroll
            for (int v = 0; v < 4; ++v) mx[v] = fmaxf(mx[v], __shfl_xor(mx[v], m));
        }
#pragma unroll
        for (int v = 0; v < 4; ++v) {
            a[v]      = __expf(a[v]      - mx[v]);
            a[4 + v]  = __expf(a[4 + v]  - mx[v]);
            a[8 + v]  = __expf(a[8 + v]  - mx[v]);
            a[12 + v] = __expf(a[12 + v] - mx[v]);
            sm[v] = a[v] + a[4 + v] + a[8 + v] + a[12 + v];
        }
#pragma unroll
        for (int m = 1; m <= 8; m <<= 1) {
#pragma unroll
            for (int v = 0; v < 4; ++v) sm[v] += __shfl_xor(sm[v], m);
        }
        float rinv[4];
#pragma unroll
        for (int v = 0; v < 4; ++v) rinv[v] = 1.f / sm[v];
#pragma unroll
        for (int v = 0; v < 4; ++v) {
            a[v] *= rinv[v]; a[4 + v] *= rinv[v];
            a[8 + v] *= rinv[v]; a[12 + v] *= rinv[v];
        }
    }
    __syncthreads();                                       // (2)
#pragma unroll
    for (int u = 0; u < 4; ++u)
        *reinterpret_cast<float4*>(&sA[(jq + u) * 68 + tq]) =
            make_float4(a[u * 4 + 0], a[u * 4 + 1], a[u * 4 + 2], a[u * 4 + 3]);
    write_w_t(pfk, sW1, tid);
    __syncthreads();                                       // (3)

    float ak[16], av[16];
#pragma unroll
    for (int u = 0; u < 16; ++u) { ak[u] = 0.f; av[u] = 0.f; }
#pragma unroll 2
    for (int i = 0; i < 64; ++i) {
        float4 wk = *reinterpret_cast<const float4*>(&sW1[i * 68 + jq]);
        float4 wv = *reinterpret_cast<const float4*>(&sW2[i * 68 + jq]);
        float4 p4 = *reinterpret_cast<const float4*>(&sA[i * 68 + tq]);
        FMA16(ak, wk, p4);
        FMA16(av, wv, p4);
    }

    {
        float ssq[4];
#pragma unroll
        for (int v = 0; v < 4; ++v)
            ssq[v] = ak[v] * ak[v] + ak[4 + v] * ak[4 + v]
                   + ak[8 + v] * ak[8 + v] + ak[12 + v] * ak[12 + v];
#pragma unroll
        for (int m = 1; m <= 8; m <<= 1) {
#pragma unroll
            for (int v = 0; v < 4; ++v) ssq[v] += __shfl_xor(ssq[v], m);
        }
#pragma unroll
        for (int v = 0; v < 4; ++v) {
            float sc = 1.f / fmaxf(sqrtf(ssq[v]), 1e-12f);
            const size_t o = (qbase + tq + v) * 64 + jq;
            *reinterpret_cast<float4*>(&ks2[o]) =
                make_float4(ak[v] * sc, ak[4 + v] * sc, ak[8 + v] * sc, ak[12 + v] * sc);
            *reinterpret_cast<float4*>(&vs2[o]) =
                make_float4(av[v], av[4 + v], av[8 + v], av[12 + v]);
        }
    }
}

// ---------------------------------------------------------------------------
// Final kernel: backward chunk-level vector pass for scan 2 + output.
// ---------------------------------------------------------------------------
__global__ __launch_bounds__(256) void final_kernel(
    const float* __restrict__ Pb, const float* __restrict__ Qb,
    const float* __restrict__ Mbuf, const float* __restrict__ qlast,
    const float* __restrict__ Wout, const float* __restrict__ bout,
    float* __restrict__ out, int nc, int chunk_stride)
{
    __shared__ float s[64], qv[64], rv[64];
    const int b = blockIdx.x;
    const int tid = threadIdx.x;
    const int r = tid >> 2;
    const int c0 = (tid & 3) * 16;

    if (tid < 64) { s[tid] = qlast[(size_t)b * 64 + tid]; qv[tid] = 0.f; }
    __syncthreads();

    for (int c = nc - 1; c >= 0; --c) {
        const size_t base = (size_t)(b * nc + c) * chunk_stride + (size_t)r * 64 + c0;
        const float4* gp = reinterpret_cast<const float4*>(Pb + base);
        const float4* gq = reinterpret_cast<const float4*>(Qb + base);
        float4 P0 = gp[0], P1 = gp[1], P2 = gp[2], P3 = gp[3];
        float4 Q0 = gq[0], Q1 = gq[1], Q2 = gq[2], Q3 = gq[3];
        const float4* sv4 = reinterpret_cast<const float4*>(&s[c0]);
        float4 s0 = sv4[0], s1 = sv4[1], s2 = sv4[2], s3 = sv4[3];

        float dp = 0.f, dq = 0.f;
        dp = fmaf(P0.x, s0.x, dp); dp = fmaf(P0.y, s0.y, dp);
        dp = fmaf(P0.z, s0.z, dp); dp = fmaf(P0.w, s0.w, dp);
        dp = fmaf(P1.x, s1.x, dp); dp = fmaf(P1.y, s1.y, dp);
        dp = fmaf(P1.z, s1.z, dp); dp = fmaf(P1.w, s1.w, dp);
        dp = fmaf(P2.x, s2.x, dp); dp = fmaf(P2.y, s2.y, dp);
        dp = fmaf(P2.z, s2.z, dp); dp = fmaf(P2.w, s2.w, dp);
        dp = fmaf(P3.x, s3.x, dp); dp = fmaf(P3.y, s3.y, dp);
        dp = fmaf(P3.z, s3.z, dp); dp = fmaf(P3.w, s3.w, dp);
        dq = fmaf(Q0.x, s0.x, dq); dq = fmaf(Q0.y, s0.y, dq);
        dq = fmaf(Q0.z, s0.z, dq); dq = fmaf(Q0.w, s0.w, dq);
        dq = fmaf(Q1.x, s1.x, dq); dq = fmaf(Q1.y, s1.y, dq);
        dq = fmaf(Q1.z, s1.z, dq); dq = fmaf(Q1.w, s1.w, dq);
        dq = fmaf(Q2.x, s2.x, dq); dq = fmaf(Q2.y, s2.y, dq);
        dq = fmaf(Q2.z, s2.z, dq); dq = fmaf(Q2.w, s2.w, dq);
        dq = fmaf(Q3.x, s3.x, dq); dq = fmaf(Q3.y, s3.y, dq);
        dq = fmaf(Q3.z, s3.z, dq); dq = fmaf(Q3.w, s3.w, dq);
        dp = dpp_xor1_add(dp); dp = dpp_xor2_add(dp);
        dq = dpp_xor1_add(dq); dq = dpp_xor2_add(dq);

        __syncthreads();
        if ((tid & 3) == 0) { s[r] = dp; qv[r] += dq; }
        __syncthreads();
    }

    {
        const float4* gm = reinterpret_cast<const float4*>(
            Mbuf + (size_t)b * 4096 + (size_t)r * 64 + c0);
        float4 M0 = gm[0], M1 = gm[1], M2v = gm[2], M3 = gm[3];
        const float4* sv4 = reinterpret_cast<const float4*>(&s[c0]);
        float4 s0 = sv4[0], s1 = sv4[1], s2 = sv4[2], s3 = sv4[3];
        float d = 0.f;
        d = fmaf(M0.x, s0.x, d); d = fmaf(M0.y, s0.y, d);
        d = fmaf(M0.z, s0.z, d); d = fmaf(M0.w, s0.w, d);
        d = fmaf(M1.x, s1.x, d); d = fmaf(M1.y, s1.y, d);
        d = fmaf(M1.z, s1.z, d); d = fmaf(M1.w, s1.w, d);
        d = fmaf(M2v.x, s2.x, d); d = fmaf(M2v.y, s2.y, d);
        d = fmaf(M2v.z, s2.z, d); d = fmaf(M2v.w, s2.w, d);
        d = fmaf(M3.x, s3.x, d); d = fmaf(M3.y, s3.y, d);
        d = fmaf(M3.z, s3.z, d); d = fmaf(M3.w, s3.w, d);
        d = dpp_xor1_add(d); d = dpp_xor2_add(d);
        if ((tid & 3) == 0) rv[r] = d + qv[r];
    }
    __syncthreads();

    if (tid < 128) {
        const float* wr = Wout + (size_t)tid * 64;
        float a0 = 0.f, a1 = 0.f, a2 = 0.f, a3 = 0.f;
#pragma unroll
        for (int h = 0; h < 64; h += 4) {
            a0 = fmaf(wr[h],     rv[h],     a0);
            a1 = fmaf(wr[h + 1], rv[h + 1], a1);
            a2 = fmaf(wr[h + 2], rv[h + 2], a2);
            a3 = fmaf(wr[h + 3], rv[h + 3], a3);
        }
        out[(size_t)b * 128 + tid] = bout[tid] + (a0 + a1) + (a2 + a3);
    }
}

// ---------------------------------------------------------------------------
extern "C" void kernel_launch(void* const* d_in, const int* in_sizes, int n_in,
                              void* d_out, int out_size, void* d_ws, size_t ws_size,
                              hipStream_t stream)
{
    const int* x        = (const int*)d_in[0];
    const float* embed  = (const float*)d_in[1];
    const float* W1     = (const float*)d_in[2];
    const float* b1     = (const float*)d_in[3];
    const float* W2     = (const float*)d_in[4];
    const float* b2     = (const float*)d_in[5];
    const float* ln_g   = (const float*)d_in[6];
    const float* ln_b   = (const float*)d_in[7];
    const float* Wk     = (const float*)d_in[8];
    const float* Wv     = (const float*)d_in[9];
    const float* Wq     = (const float*)d_in[10];
    const float* Wattn  = (const float*)d_in[11];
    const float* Wout   = (const float*)d_in[12];
    const float* bout   = (const float*)d_in[13];

    // workspace (floats): ks | vs | hidT | qlast | M | WAM | MK | MV
    float* ws = (float*)d_ws;
    float* ks  = ws;
    float* vs  = ks  + (size_t)NB * SEQL * 64;
    float* hid = vs  + (size_t)NB * SEQL * 64;
    float* ql  = hid + (size_t)NB * 2048 * 64;
    float* M   = ql  + (size_t)NB * 64;
    float* WAM = M   + (size_t)NB * 64 * 64;
    float* MK  = WAM + (size_t)NB * 64 * 64;
    float* MV  = MK  + (size_t)NB * 64 * 64;
    if (ws_size < (size_t)(MV + (size_t)NB * 64 * 64 - ws) * sizeof(float)) return;

    hipLaunchKernelGGL(encoder_kernel, dim3((NB * SEQL) / 64), dim3(256), 0, stream,
                       x, embed, W1, b1, W2, b2, ln_g, ln_b, Wk, Wv, Wq,
                       ks, vs, hid, ql);

    // scan 1: L=4096, C=256 -> 16 chunks/batch (matrix combine; M needed in full)
    const int C1 = 256, nc1 = SEQL / C1;
    hipLaunchKernelGGL(chunk_kernel, dim3(NB * nc1), dim3(256), 0, stream, ks, vs, C1);
    hipLaunchKernelGGL(combine_kernel, dim3(NB * 4), dim3(256), 0, stream,
                       ks, vs, (const float*)nullptr, M, nc1, C1 * 64);

    // per-batch fused operands
    hipLaunchKernelGGL(precompute_kernel, dim3(NB), dim3(256), 0, stream,
                       M, Wattn, Wk, Wv, WAM, MK, MV);

    // attention + second k/v projection (ks2/vs2 reuse ks/vs)
    hipLaunchKernelGGL(attn_kernel, dim3(32, NB), dim3(256), 0, stream,
                       hid, WAM, MK, MV, ks, vs);

    // scan 2: L=2048, C=128 -> 16 chunks/batch; final = backward vector pass
    const int C2 = 128, nc2 = 2048 / C2;
    hipLaunchKernelGGL(chunk_kernel, dim3(NB * nc2), dim3(256), 0, stream, ks, vs, C2);
    hipLaunchKernelGGL(final_kernel, dim3(NB), dim3(256), 0, stream,
                       ks, vs, M, ql, Wout, bout, (float*)d_out, nc2, C2 * 64);
}